// Round 5
// baseline (484.284 us; speedup 1.0000x reference)
//
#include <hip/hip_runtime.h>
#include <math.h>

#define BB 256
#define L 512
#define NSIG 50
#define PAD 4
#define STR (L + 2 * PAD)   // 520 floats per padded row

__device__ __forceinline__ int refl(int i) {
    if (i < 0) i = -i;
    if (i >= L) i = 2 * L - 2 - i;
    return i;
}

__device__ __forceinline__ float selu(float x) {
    const float scale = 1.0507009873554804934193349852946f;
    const float alpha = 1.6732632423543772848170429916717f;
    return x > 0.f ? scale * x : scale * alpha * (__expf(x) - 1.f);
}

// Edge threads mirror their own freshly-computed pair into the reflect halo.
// Pair (v0,v1) sits at positions (p0, p0+1) = (2t, 2t+1). halo[-1-i] = x[1+i],
// halo[L+i] = x[L-2-i]. W = halo width needed by the consumer.
__device__ __forceinline__ void halo_w(float* row, int t, float v0, float v1, int W) {
    if (t == 0)               row[PAD - 1] = v1;               // x[1]
    if (t == 1) {             row[PAD - 2] = v0;               // x[2]
        if (W >= 3)           row[PAD - 3] = v1; }             // x[3]
    if (t == 2 && W >= 4)     row[PAD - 4] = v0;               // x[4]
    if (t == 255)             row[PAD + L] = v0;               // x[510]
    if (t == 254) {           row[PAD + L + 1] = v1;           // x[509]
        if (W >= 3)           row[PAD + L + 2] = v0; }         // x[508]
    if (t == 253 && W >= 4)   row[PAD + L + 3] = v1;           // x[507]
}

// ---------------- Kernel A: sharedCNN x2 + residual + LayerNorm ----------------
__global__ __launch_bounds__(256) void shared_ln_kernel(
    const float* __restrict__ latent,   // (B, 2048)
    const float* __restrict__ w1, const float* __restrict__ b1,   // (8,4,5),(8,)
    const float* __restrict__ w2, const float* __restrict__ b2,   // (4,8,5),(4,)
    const float* __restrict__ g,  const float* __restrict__ beta, // (512,),(512,)
    float* __restrict__ D)              // (B,4,512)
{
    __shared__ float xb[4][L];
    __shared__ float hb[8][L];
    __shared__ float yb[4][L];
    __shared__ float sw1[160], sb1[8], sw2[160], sb2[4];

    const int b = blockIdx.x;
    const int t = threadIdx.x;

    for (int i = t; i < 160; i += 256) { sw1[i] = w1[i]; sw2[i] = w2[i]; }
    if (t < 8) sb1[t] = b1[t];
    if (t < 4) sb2[t] = b2[t];

    const float* lp = latent + (size_t)b * 2048;
    for (int i = t; i < 2048; i += 256)
        xb[i & 3][i >> 2] = lp[i];   // x[c][l] = latent[l*4+c]
    __syncthreads();

    for (int pass = 0; pass < 2; ++pass) {
        const float (*src)[L] = (pass == 0) ? (const float (*)[L])xb
                                            : (const float (*)[L])yb;
        // conv1: 4->8, k5, d1, pad2, SELU
        for (int idx = t; idx < 8 * L; idx += 256) {
            int co = idx >> 9, l = idx & (L - 1);
            float acc = sb1[co];
            #pragma unroll
            for (int ci = 0; ci < 4; ++ci) {
                const float* w = &sw1[(co * 4 + ci) * 5];
                #pragma unroll
                for (int k = 0; k < 5; ++k)
                    acc += w[k] * src[ci][refl(l + k - 2)];
            }
            hb[co][l] = selu(acc);
        }
        __syncthreads();
        // conv2: 8->4, k5, d2, pad4 (+ residual on pass 1)
        for (int idx = t; idx < 4 * L; idx += 256) {
            int co = idx >> 9, l = idx & (L - 1);
            float acc = sb2[co];
            #pragma unroll
            for (int ci = 0; ci < 8; ++ci) {
                const float* w = &sw2[(co * 8 + ci) * 5];
                #pragma unroll
                for (int k = 0; k < 5; ++k)
                    acc += w[k] * hb[ci][refl(l + 2 * k - 4)];
            }
            if (pass == 1) acc += xb[co][l];
            yb[co][l] = acc;
        }
        __syncthreads();
    }

    // LayerNorm over length axis, one wave per channel (4 waves = 256 threads)
    const int wave = t >> 6;    // channel 0..3
    const int lane = t & 63;
    float v[8];
    float s = 0.f;
    #pragma unroll
    for (int j = 0; j < 8; ++j) { v[j] = yb[wave][lane * 8 + j]; s += v[j]; }
    #pragma unroll
    for (int off = 32; off > 0; off >>= 1) s += __shfl_down(s, off);
    s = __shfl(s, 0);
    const float mu = s * (1.f / 512.f);
    float s2 = 0.f;
    #pragma unroll
    for (int j = 0; j < 8; ++j) { float d = v[j] - mu; s2 += d * d; }
    #pragma unroll
    for (int off = 32; off > 0; off >>= 1) s2 += __shfl_down(s2, off);
    s2 = __shfl(s2, 0);
    const float rinv = rsqrtf(s2 * (1.f / 512.f) + 1e-10f);

    float* Dp = D + ((size_t)b * 4 + wave) * L;
    #pragma unroll
    for (int j = 0; j < 8; ++j) {
        int l = lane * 8 + j;
        Dp[l] = (v[j] - mu) * rinv * g[l] + beta[l];
    }
}

// ---------------- Kernel B: per-signal channel-reduction stack ----------------
// 256 threads, P=2 (p0 = 2t). LDS = 8 rows x 520 = 16.6 KB -> 8 blocks/CU =
// 32 waves/CU (100% cap). conv1/conv2 split in co/ci halves so h1 needs only
// 4 LDS rows; conv2 accumulators live in registers across the two halves.
// All window reads are aligned float2 (b64, 2-way bank alias = free). Halo
// stores fused into producing phase -> 6 barriers total. Weights via uniform
// s_load (blockIdx-indexed).
__global__ __launch_bounds__(256, 8) void signal_kernel(
    const float* __restrict__ D,   // (B,4,512)
    const float* __restrict__ w1, const float* __restrict__ b1, // (50,8,4,7),(50,8)
    const float* __restrict__ w2, const float* __restrict__ b2, // (50,4,8,5),(50,4)
    const float* __restrict__ w3, const float* __restrict__ b3, // (50,2,4,5),(50,2)
    const float* __restrict__ w4, const float* __restrict__ b4, // (50,1,2,5),(50,1)
    float* __restrict__ out)       // (B,50,512)
{
    const int s = blockIdx.x;
    const int b = blockIdx.y;
    const int t = threadIdx.x;     // 0..255
    const int p0 = t * 2;

    __shared__ float Xb[4][STR];   // db, then h2
    __shared__ float Yb[4][STR];   // h1 (half at a time), then h3 (rows 0..1)

    const float* W1 = w1 + s * 224; const float* B1 = b1 + s * 8;
    const float* W2 = w2 + s * 160; const float* B2 = b2 + s * 4;
    const float* W3 = w3 + s * 40;  const float* B3 = b3 + s * 2;
    const float* W4 = w4 + s * 10;

    // ---- stage db into Xb (+ fused halo, width 3) ----
    {
        const float4* Dv = (const float4*)(D + (size_t)b * 2048);
        #pragma unroll
        for (int j = 0; j < 2; ++j) {
            int i = t + j * 256;               // float4 index 0..511
            float4 v = Dv[i];
            int c = i >> 7, col = (i & 127) << 2;
            *(float4*)&Xb[c][PAD + col] = v;
            if ((i & 127) == 0) {              // holds x0..x3
                Xb[c][PAD - 1] = v.y; Xb[c][PAD - 2] = v.z; Xb[c][PAD - 3] = v.w;
            }
            if ((i & 127) == 127) {            // holds x508..x511
                Xb[c][PAD + L] = v.z; Xb[c][PAD + L + 1] = v.y; Xb[c][PAD + L + 2] = v.x;
            }
        }
    }
    __syncthreads();   // B1

    float acc2[4][2];  // conv2 accumulators, live across both halves
    #pragma unroll
    for (int co = 0; co < 4; ++co) {
        float bb = B2[co];
        acc2[co][0] = bb; acc2[co][1] = bb;
    }

    #pragma unroll
    for (int half = 0; half < 2; ++half) {
        // ---- conv1 half: co = half*4 .. half*4+3, k7, pad3, reads Xb ----
        float a1[4][2];
        #pragma unroll
        for (int co = 0; co < 4; ++co) {
            float bb = B1[half * 4 + co];
            a1[co][0] = bb; a1[co][1] = bb;
        }
        #pragma unroll
        for (int ci = 0; ci < 4; ++ci) {
            float x[10];                       // positions p0-4 .. p0+5
            const float* row = &Xb[ci][p0];    // element index PAD + p0 - 4
            *(float2*)&x[0] = *(const float2*)&row[0];
            *(float2*)&x[2] = *(const float2*)&row[2];
            *(float2*)&x[4] = *(const float2*)&row[4];
            *(float2*)&x[6] = *(const float2*)&row[6];
            *(float2*)&x[8] = *(const float2*)&row[8];
            #pragma unroll
            for (int co = 0; co < 4; ++co)
                #pragma unroll
                for (int k = 0; k < 7; ++k) {
                    float w = W1[((half * 4 + co) * 4 + ci) * 7 + k];
                    a1[co][0] += w * x[k + 1];
                    a1[co][1] += w * x[k + 2];
                }
        }
        if (half == 1) __syncthreads();        // B3: conv2a reads of Yb done
        #pragma unroll
        for (int co = 0; co < 4; ++co) {
            float2 v = { a1[co][0], a1[co][1] };
            *(float2*)&Yb[co][PAD + p0] = v;
            halo_w(Yb[co], t, v.x, v.y, 2);
        }
        __syncthreads();                       // B2 / B4: h1 half ready

        // ---- conv2 partial: ci = half*4 .. half*4+3, k5, pad2, reads Yb ----
        #pragma unroll
        for (int ci = 0; ci < 4; ++ci) {
            float x[8];                            // positions p0-2 .. p0+5
            const float* row = &Yb[ci][p0 + 2];    // element index PAD + p0 - 2
            *(float2*)&x[0] = *(const float2*)&row[0];
            *(float2*)&x[2] = *(const float2*)&row[2];
            *(float2*)&x[4] = *(const float2*)&row[4];
            *(float2*)&x[6] = *(const float2*)&row[6];
            #pragma unroll
            for (int co = 0; co < 4; ++co)
                #pragma unroll
                for (int k = 0; k < 5; ++k) {
                    float w = W2[(co * 8 + half * 4 + ci) * 5 + k];
                    acc2[co][0] += w * x[k];
                    acc2[co][1] += w * x[k + 1];
                }
        }
    }

    // ---- SELU + write h2 into Xb (db dead; last Xb reads were pre-B4) ----
    #pragma unroll
    for (int co = 0; co < 4; ++co) {
        float2 v = { selu(acc2[co][0]), selu(acc2[co][1]) };
        *(float2*)&Xb[co][PAD + p0] = v;
        halo_w(Xb[co], t, v.x, v.y, 2);
    }
    __syncthreads();                           // B5

    // ---- conv3: 4->2, k5, pad2, reads Xb, writes Yb rows 0..1 (halo 4) ----
    {
        float a3[2][2];
        #pragma unroll
        for (int co = 0; co < 2; ++co) {
            float bb = B3[co];
            a3[co][0] = bb; a3[co][1] = bb;
        }
        #pragma unroll
        for (int ci = 0; ci < 4; ++ci) {
            float x[8];
            const float* row = &Xb[ci][p0 + 2];
            *(float2*)&x[0] = *(const float2*)&row[0];
            *(float2*)&x[2] = *(const float2*)&row[2];
            *(float2*)&x[4] = *(const float2*)&row[4];
            *(float2*)&x[6] = *(const float2*)&row[6];
            #pragma unroll
            for (int co = 0; co < 2; ++co)
                #pragma unroll
                for (int k = 0; k < 5; ++k) {
                    float w = W3[(co * 4 + ci) * 5 + k];
                    a3[co][0] += w * x[k];
                    a3[co][1] += w * x[k + 1];
                }
        }
        #pragma unroll
        for (int co = 0; co < 2; ++co) {
            float2 v = { a3[co][0], a3[co][1] };
            *(float2*)&Yb[co][PAD + p0] = v;
            halo_w(Yb[co], t, v.x, v.y, 4);
        }
    }
    __syncthreads();                           // B6

    // ---- conv4: 2->1, k5, d2, pad4, SELU, reads Yb rows 0..1 -> out ----
    {
        float a0 = b4[s], a1v = a0;
        #pragma unroll
        for (int ci = 0; ci < 2; ++ci) {
            float x[10];                       // positions p0-4 .. p0+5
            const float* row = &Yb[ci][p0];
            *(float2*)&x[0] = *(const float2*)&row[0];
            *(float2*)&x[2] = *(const float2*)&row[2];
            *(float2*)&x[4] = *(const float2*)&row[4];
            *(float2*)&x[6] = *(const float2*)&row[6];
            *(float2*)&x[8] = *(const float2*)&row[8];
            #pragma unroll
            for (int k = 0; k < 5; ++k) {
                float w = W4[ci * 5 + k];
                a0  += w * x[2 * k];
                a1v += w * x[2 * k + 1];
            }
        }
        float2 r = { selu(a0), selu(a1v) };
        *(float2*)&out[((size_t)b * NSIG + s) * L + p0] = r;
    }
}

extern "C" void kernel_launch(void* const* d_in, const int* in_sizes, int n_in,
                              void* d_out, int out_size, void* d_ws, size_t ws_size,
                              hipStream_t stream) {
    const float* latent = (const float*)d_in[0];
    const float* sw1 = (const float*)d_in[1];
    const float* sb1 = (const float*)d_in[2];
    const float* sw2 = (const float*)d_in[3];
    const float* sb2 = (const float*)d_in[4];
    const float* ln_g = (const float*)d_in[5];
    const float* ln_b = (const float*)d_in[6];
    const float* g_w1 = (const float*)d_in[7];
    const float* g_b1 = (const float*)d_in[8];
    const float* g_w2 = (const float*)d_in[9];
    const float* g_b2 = (const float*)d_in[10];
    const float* g_w3 = (const float*)d_in[11];
    const float* g_b3 = (const float*)d_in[12];
    const float* g_w4 = (const float*)d_in[13];
    const float* g_b4 = (const float*)d_in[14];
    float* out = (float*)d_out;
    float* D = (float*)d_ws;   // (256,4,512) f32 = 2 MB

    shared_ln_kernel<<<BB, 256, 0, stream>>>(latent, sw1, sb1, sw2, sb2,
                                             ln_g, ln_b, D);
    signal_kernel<<<dim3(NSIG, BB), 256, 0, stream>>>(D, g_w1, g_b1, g_w2, g_b2,
                                                      g_w3, g_b3, g_w4, g_b4, out);
}

// Round 6
// 162.770 us; speedup vs baseline: 2.9753x; 2.9753x over previous
//
#include <hip/hip_runtime.h>
#include <math.h>

#define BB 256
#define L 512
#define NSIG 50
#define PAD 4
#define STR (L + 2 * PAD)   // 520 floats per padded row

__device__ __forceinline__ int refl(int i) {
    if (i < 0) i = -i;
    if (i >= L) i = 2 * L - 2 - i;
    return i;
}

__device__ __forceinline__ float selu(float x) {
    const float scale = 1.0507009873554804934193349852946f;
    const float alpha = 1.6732632423543772848170429916717f;
    return x > 0.f ? scale * x : scale * alpha * (__expf(x) - 1.f);
}

// Edge threads mirror their own freshly-computed pair into the reflect halo.
// Pair (v0,v1) sits at positions (p0, p0+1) = (2t, 2t+1). halo[-1-i] = x[1+i],
// halo[L+i] = x[L-2-i]. W = halo width needed by the consumer.
__device__ __forceinline__ void halo_w(float* row, int t, float v0, float v1, int W) {
    if (t == 0)               row[PAD - 1] = v1;               // x[1]
    if (t == 1) {             row[PAD - 2] = v0;               // x[2]
        if (W >= 3)           row[PAD - 3] = v1; }             // x[3]
    if (t == 2 && W >= 4)     row[PAD - 4] = v0;               // x[4]
    if (t == 255)             row[PAD + L] = v0;               // x[510]
    if (t == 254) {           row[PAD + L + 1] = v1;           // x[509]
        if (W >= 3)           row[PAD + L + 2] = v0; }         // x[508]
    if (t == 253 && W >= 4)   row[PAD + L + 3] = v1;           // x[507]
}

// ---------------- Kernel A: sharedCNN x2 + residual + LayerNorm ----------------
__global__ __launch_bounds__(256) void shared_ln_kernel(
    const float* __restrict__ latent,   // (B, 2048)
    const float* __restrict__ w1, const float* __restrict__ b1,   // (8,4,5),(8,)
    const float* __restrict__ w2, const float* __restrict__ b2,   // (4,8,5),(4,)
    const float* __restrict__ g,  const float* __restrict__ beta, // (512,),(512,)
    float* __restrict__ D)              // (B,4,512)
{
    __shared__ float xb[4][L];
    __shared__ float hb[8][L];
    __shared__ float yb[4][L];
    __shared__ float sw1[160], sb1[8], sw2[160], sb2[4];

    const int b = blockIdx.x;
    const int t = threadIdx.x;

    for (int i = t; i < 160; i += 256) { sw1[i] = w1[i]; sw2[i] = w2[i]; }
    if (t < 8) sb1[t] = b1[t];
    if (t < 4) sb2[t] = b2[t];

    const float* lp = latent + (size_t)b * 2048;
    for (int i = t; i < 2048; i += 256)
        xb[i & 3][i >> 2] = lp[i];   // x[c][l] = latent[l*4+c]
    __syncthreads();

    for (int pass = 0; pass < 2; ++pass) {
        const float (*src)[L] = (pass == 0) ? (const float (*)[L])xb
                                            : (const float (*)[L])yb;
        // conv1: 4->8, k5, d1, pad2, SELU
        for (int idx = t; idx < 8 * L; idx += 256) {
            int co = idx >> 9, l = idx & (L - 1);
            float acc = sb1[co];
            #pragma unroll
            for (int ci = 0; ci < 4; ++ci) {
                const float* w = &sw1[(co * 4 + ci) * 5];
                #pragma unroll
                for (int k = 0; k < 5; ++k)
                    acc += w[k] * src[ci][refl(l + k - 2)];
            }
            hb[co][l] = selu(acc);
        }
        __syncthreads();
        // conv2: 8->4, k5, d2, pad4 (+ residual on pass 1)
        for (int idx = t; idx < 4 * L; idx += 256) {
            int co = idx >> 9, l = idx & (L - 1);
            float acc = sb2[co];
            #pragma unroll
            for (int ci = 0; ci < 8; ++ci) {
                const float* w = &sw2[(co * 8 + ci) * 5];
                #pragma unroll
                for (int k = 0; k < 5; ++k)
                    acc += w[k] * hb[ci][refl(l + 2 * k - 4)];
            }
            if (pass == 1) acc += xb[co][l];
            yb[co][l] = acc;
        }
        __syncthreads();
    }

    // LayerNorm over length axis, one wave per channel (4 waves = 256 threads)
    const int wave = t >> 6;    // channel 0..3
    const int lane = t & 63;
    float v[8];
    float s = 0.f;
    #pragma unroll
    for (int j = 0; j < 8; ++j) { v[j] = yb[wave][lane * 8 + j]; s += v[j]; }
    #pragma unroll
    for (int off = 32; off > 0; off >>= 1) s += __shfl_down(s, off);
    s = __shfl(s, 0);
    const float mu = s * (1.f / 512.f);
    float s2 = 0.f;
    #pragma unroll
    for (int j = 0; j < 8; ++j) { float d = v[j] - mu; s2 += d * d; }
    #pragma unroll
    for (int off = 32; off > 0; off >>= 1) s2 += __shfl_down(s2, off);
    s2 = __shfl(s2, 0);
    const float rinv = rsqrtf(s2 * (1.f / 512.f) + 1e-10f);

    float* Dp = D + ((size_t)b * 4 + wave) * L;
    #pragma unroll
    for (int j = 0; j < 8; ++j) {
        int l = lane * 8 + j;
        Dp[l] = (v[j] - mu) * rinv * g[l] + beta[l];
    }
}

// ---------------- Kernel B: per-signal channel-reduction stack ----------------
// 256 threads, P=2 (p0 = 2t). LDS = 8 rows x 520 = 16.6 KB -> 8 blocks/CU =
// 32 waves/CU cap. conv1/conv2 split in co/ci halves so h1 needs only 4 LDS
// rows; conv2 accumulators live in registers across the two halves. All
// window reads aligned float2 (b64, 2-way alias = free). Halo stores fused
// into producing phase -> 6 barriers. Weights via uniform s_load.
// NOTE: no min-waves clamp — __launch_bounds__(256,8) forced VGPR=32 and
// spilled everything to scratch (830MB fetch, 2GB traffic, 5x slowdown).
__global__ __launch_bounds__(256) void signal_kernel(
    const float* __restrict__ D,   // (B,4,512)
    const float* __restrict__ w1, const float* __restrict__ b1, // (50,8,4,7),(50,8)
    const float* __restrict__ w2, const float* __restrict__ b2, // (50,4,8,5),(50,4)
    const float* __restrict__ w3, const float* __restrict__ b3, // (50,2,4,5),(50,2)
    const float* __restrict__ w4, const float* __restrict__ b4, // (50,1,2,5),(50,1)
    float* __restrict__ out)       // (B,50,512)
{
    const int s = blockIdx.x;
    const int b = blockIdx.y;
    const int t = threadIdx.x;     // 0..255
    const int p0 = t * 2;

    __shared__ float Xb[4][STR];   // db, then h2
    __shared__ float Yb[4][STR];   // h1 (half at a time), then h3 (rows 0..1)

    const float* W1 = w1 + s * 224; const float* B1 = b1 + s * 8;
    const float* W2 = w2 + s * 160; const float* B2 = b2 + s * 4;
    const float* W3 = w3 + s * 40;  const float* B3 = b3 + s * 2;
    const float* W4 = w4 + s * 10;

    // ---- stage db into Xb (+ fused halo, width 3) ----
    {
        const float4* Dv = (const float4*)(D + (size_t)b * 2048);
        #pragma unroll
        for (int j = 0; j < 2; ++j) {
            int i = t + j * 256;               // float4 index 0..511
            float4 v = Dv[i];
            int c = i >> 7, col = (i & 127) << 2;
            *(float4*)&Xb[c][PAD + col] = v;
            if ((i & 127) == 0) {              // holds x0..x3
                Xb[c][PAD - 1] = v.y; Xb[c][PAD - 2] = v.z; Xb[c][PAD - 3] = v.w;
            }
            if ((i & 127) == 127) {            // holds x508..x511
                Xb[c][PAD + L] = v.z; Xb[c][PAD + L + 1] = v.y; Xb[c][PAD + L + 2] = v.x;
            }
        }
    }
    __syncthreads();   // B1

    float acc2[4][2];  // conv2 accumulators, live across both halves
    #pragma unroll
    for (int co = 0; co < 4; ++co) {
        float bb = B2[co];
        acc2[co][0] = bb; acc2[co][1] = bb;
    }

    #pragma unroll
    for (int half = 0; half < 2; ++half) {
        // ---- conv1 half: co = half*4 .. half*4+3, k7, pad3, reads Xb ----
        float a1[4][2];
        #pragma unroll
        for (int co = 0; co < 4; ++co) {
            float bb = B1[half * 4 + co];
            a1[co][0] = bb; a1[co][1] = bb;
        }
        #pragma unroll
        for (int ci = 0; ci < 4; ++ci) {
            float x[10];                       // positions p0-4 .. p0+5
            const float* row = &Xb[ci][p0];    // element index PAD + p0 - 4
            *(float2*)&x[0] = *(const float2*)&row[0];
            *(float2*)&x[2] = *(const float2*)&row[2];
            *(float2*)&x[4] = *(const float2*)&row[4];
            *(float2*)&x[6] = *(const float2*)&row[6];
            *(float2*)&x[8] = *(const float2*)&row[8];
            #pragma unroll
            for (int co = 0; co < 4; ++co)
                #pragma unroll
                for (int k = 0; k < 7; ++k) {
                    float w = W1[((half * 4 + co) * 4 + ci) * 7 + k];
                    a1[co][0] += w * x[k + 1];
                    a1[co][1] += w * x[k + 2];
                }
        }
        if (half == 1) __syncthreads();        // B3: conv2a reads of Yb done
        #pragma unroll
        for (int co = 0; co < 4; ++co) {
            float2 v = { a1[co][0], a1[co][1] };
            *(float2*)&Yb[co][PAD + p0] = v;
            halo_w(Yb[co], t, v.x, v.y, 2);
        }
        __syncthreads();                       // B2 / B4: h1 half ready

        // ---- conv2 partial: ci = half*4 .. half*4+3, k5, pad2, reads Yb ----
        #pragma unroll
        for (int ci = 0; ci < 4; ++ci) {
            float x[8];                            // positions p0-2 .. p0+5
            const float* row = &Yb[ci][p0 + 2];    // element index PAD + p0 - 2
            *(float2*)&x[0] = *(const float2*)&row[0];
            *(float2*)&x[2] = *(const float2*)&row[2];
            *(float2*)&x[4] = *(const float2*)&row[4];
            *(float2*)&x[6] = *(const float2*)&row[6];
            #pragma unroll
            for (int co = 0; co < 4; ++co)
                #pragma unroll
                for (int k = 0; k < 5; ++k) {
                    float w = W2[(co * 8 + half * 4 + ci) * 5 + k];
                    acc2[co][0] += w * x[k];
                    acc2[co][1] += w * x[k + 1];
                }
        }
    }

    // ---- SELU + write h2 into Xb (db dead; last Xb reads were pre-B4) ----
    #pragma unroll
    for (int co = 0; co < 4; ++co) {
        float2 v = { selu(acc2[co][0]), selu(acc2[co][1]) };
        *(float2*)&Xb[co][PAD + p0] = v;
        halo_w(Xb[co], t, v.x, v.y, 2);
    }
    __syncthreads();                           // B5

    // ---- conv3: 4->2, k5, pad2, reads Xb, writes Yb rows 0..1 (halo 4) ----
    {
        float a3[2][2];
        #pragma unroll
        for (int co = 0; co < 2; ++co) {
            float bb = B3[co];
            a3[co][0] = bb; a3[co][1] = bb;
        }
        #pragma unroll
        for (int ci = 0; ci < 4; ++ci) {
            float x[8];
            const float* row = &Xb[ci][p0 + 2];
            *(float2*)&x[0] = *(const float2*)&row[0];
            *(float2*)&x[2] = *(const float2*)&row[2];
            *(float2*)&x[4] = *(const float2*)&row[4];
            *(float2*)&x[6] = *(const float2*)&row[6];
            #pragma unroll
            for (int co = 0; co < 2; ++co)
                #pragma unroll
                for (int k = 0; k < 5; ++k) {
                    float w = W3[(co * 4 + ci) * 5 + k];
                    a3[co][0] += w * x[k];
                    a3[co][1] += w * x[k + 1];
                }
        }
        #pragma unroll
        for (int co = 0; co < 2; ++co) {
            float2 v = { a3[co][0], a3[co][1] };
            *(float2*)&Yb[co][PAD + p0] = v;
            halo_w(Yb[co], t, v.x, v.y, 4);
        }
    }
    __syncthreads();                           // B6

    // ---- conv4: 2->1, k5, d2, pad4, SELU, reads Yb rows 0..1 -> out ----
    {
        float a0 = b4[s], a1v = a0;
        #pragma unroll
        for (int ci = 0; ci < 2; ++ci) {
            float x[10];                       // positions p0-4 .. p0+5
            const float* row = &Yb[ci][p0];
            *(float2*)&x[0] = *(const float2*)&row[0];
            *(float2*)&x[2] = *(const float2*)&row[2];
            *(float2*)&x[4] = *(const float2*)&row[4];
            *(float2*)&x[6] = *(const float2*)&row[6];
            *(float2*)&x[8] = *(const float2*)&row[8];
            #pragma unroll
            for (int k = 0; k < 5; ++k) {
                float w = W4[ci * 5 + k];
                a0  += w * x[2 * k];
                a1v += w * x[2 * k + 1];
            }
        }
        float2 r = { selu(a0), selu(a1v) };
        *(float2*)&out[((size_t)b * NSIG + s) * L + p0] = r;
    }
}

extern "C" void kernel_launch(void* const* d_in, const int* in_sizes, int n_in,
                              void* d_out, int out_size, void* d_ws, size_t ws_size,
                              hipStream_t stream) {
    const float* latent = (const float*)d_in[0];
    const float* sw1 = (const float*)d_in[1];
    const float* sb1 = (const float*)d_in[2];
    const float* sw2 = (const float*)d_in[3];
    const float* sb2 = (const float*)d_in[4];
    const float* ln_g = (const float*)d_in[5];
    const float* ln_b = (const float*)d_in[6];
    const float* g_w1 = (const float*)d_in[7];
    const float* g_b1 = (const float*)d_in[8];
    const float* g_w2 = (const float*)d_in[9];
    const float* g_b2 = (const float*)d_in[10];
    const float* g_w3 = (const float*)d_in[11];
    const float* g_b3 = (const float*)d_in[12];
    const float* g_w4 = (const float*)d_in[13];
    const float* g_b4 = (const float*)d_in[14];
    float* out = (float*)d_out;
    float* D = (float*)d_ws;   // (256,4,512) f32 = 2 MB

    shared_ln_kernel<<<BB, 256, 0, stream>>>(latent, sw1, sb1, sw2, sb2,
                                             ln_g, ln_b, D);
    signal_kernel<<<dim3(NSIG, BB), 256, 0, stream>>>(D, g_w1, g_b1, g_w2, g_b2,
                                                      g_w3, g_b3, g_w4, g_b4, out);
}

// Round 7
// 150.616 us; speedup vs baseline: 3.2154x; 1.0807x over previous
//
#include <hip/hip_runtime.h>
#include <math.h>

#define BB 256
#define L 512
#define NSIG 50
#define PAD 4
#define STR (L + 2 * PAD)   // 520 floats per padded row

__device__ __forceinline__ int refl(int i) {
    if (i < 0) i = -i;
    if (i >= L) i = 2 * L - 2 - i;
    return i;
}

__device__ __forceinline__ float selu(float x) {
    const float scale = 1.0507009873554804934193349852946f;
    const float alpha = 1.6732632423543772848170429916717f;
    return x > 0.f ? scale * x : scale * alpha * (__expf(x) - 1.f);
}

// ---------------- Kernel A: sharedCNN x2 + residual + LayerNorm ----------------
__global__ __launch_bounds__(256) void shared_ln_kernel(
    const float* __restrict__ latent,   // (B, 2048)
    const float* __restrict__ w1, const float* __restrict__ b1,   // (8,4,5),(8,)
    const float* __restrict__ w2, const float* __restrict__ b2,   // (4,8,5),(4,)
    const float* __restrict__ g,  const float* __restrict__ beta, // (512,),(512,)
    float* __restrict__ D)              // (B,4,512)
{
    __shared__ float xb[4][L];
    __shared__ float hb[8][L];
    __shared__ float yb[4][L];
    __shared__ float sw1[160], sb1[8], sw2[160], sb2[4];

    const int b = blockIdx.x;
    const int t = threadIdx.x;

    for (int i = t; i < 160; i += 256) { sw1[i] = w1[i]; sw2[i] = w2[i]; }
    if (t < 8) sb1[t] = b1[t];
    if (t < 4) sb2[t] = b2[t];

    const float* lp = latent + (size_t)b * 2048;
    for (int i = t; i < 2048; i += 256)
        xb[i & 3][i >> 2] = lp[i];   // x[c][l] = latent[l*4+c]
    __syncthreads();

    for (int pass = 0; pass < 2; ++pass) {
        const float (*src)[L] = (pass == 0) ? (const float (*)[L])xb
                                            : (const float (*)[L])yb;
        // conv1: 4->8, k5, d1, pad2, SELU
        for (int idx = t; idx < 8 * L; idx += 256) {
            int co = idx >> 9, l = idx & (L - 1);
            float acc = sb1[co];
            #pragma unroll
            for (int ci = 0; ci < 4; ++ci) {
                const float* w = &sw1[(co * 4 + ci) * 5];
                #pragma unroll
                for (int k = 0; k < 5; ++k)
                    acc += w[k] * src[ci][refl(l + k - 2)];
            }
            hb[co][l] = selu(acc);
        }
        __syncthreads();
        // conv2: 8->4, k5, d2, pad4 (+ residual on pass 1)
        for (int idx = t; idx < 4 * L; idx += 256) {
            int co = idx >> 9, l = idx & (L - 1);
            float acc = sb2[co];
            #pragma unroll
            for (int ci = 0; ci < 8; ++ci) {
                const float* w = &sw2[(co * 8 + ci) * 5];
                #pragma unroll
                for (int k = 0; k < 5; ++k)
                    acc += w[k] * hb[ci][refl(l + 2 * k - 4)];
            }
            if (pass == 1) acc += xb[co][l];
            yb[co][l] = acc;
        }
        __syncthreads();
    }

    // LayerNorm over length axis, one wave per channel (4 waves = 256 threads)
    const int wave = t >> 6;    // channel 0..3
    const int lane = t & 63;
    float v[8];
    float s = 0.f;
    #pragma unroll
    for (int j = 0; j < 8; ++j) { v[j] = yb[wave][lane * 8 + j]; s += v[j]; }
    #pragma unroll
    for (int off = 32; off > 0; off >>= 1) s += __shfl_down(s, off);
    s = __shfl(s, 0);
    const float mu = s * (1.f / 512.f);
    float s2 = 0.f;
    #pragma unroll
    for (int j = 0; j < 8; ++j) { float d = v[j] - mu; s2 += d * d; }
    #pragma unroll
    for (int off = 32; off > 0; off >>= 1) s2 += __shfl_down(s2, off);
    s2 = __shfl(s2, 0);
    const float rinv = rsqrtf(s2 * (1.f / 512.f) + 1e-10f);

    float* Dp = D + ((size_t)b * 4 + wave) * L;
    #pragma unroll
    for (int j = 0; j < 8; ++j) {
        int l = lane * 8 + j;
        Dp[l] = (v[j] - mu) * rinv * g[l] + beta[l];
    }
}

// ---------------- Kernel B: per-signal channel-reduction stack ----------------
// One wave (64 thr) per (s,b); lane owns 8 positions (p0 = 8*lane). conv1
// windows come straight from global (D is L2-resident) -> no db staging.
// Single 4-row LDS buffer (8.3 KB -> 19 blocks/CU); conv1/conv2 split in
// halves so h1 only ever needs 4 rows; acc2 lives in registers across halves.
// All LDS reads aligned b64/b128 (~10 LDS ops per output position total).
// Reflect halo pre-stored by edge lanes (their own registers). Weights via
// uniform s_load. 7 one-wave barriers.
__global__ __launch_bounds__(64) void signal_kernel(
    const float* __restrict__ D,   // (B,4,512)
    const float* __restrict__ w1, const float* __restrict__ b1, // (50,8,4,7),(50,8)
    const float* __restrict__ w2, const float* __restrict__ b2, // (50,4,8,5),(50,4)
    const float* __restrict__ w3, const float* __restrict__ b3, // (50,2,4,5),(50,2)
    const float* __restrict__ w4, const float* __restrict__ b4, // (50,1,2,5),(50,1)
    float* __restrict__ out)       // (B,50,512)
{
    const int s = blockIdx.x;
    const int b = blockIdx.y;
    const int lane = threadIdx.x;  // 0..63
    const int p0 = lane * 8;

    __shared__ float H[4][STR];    // h1 (half at a time), h2, h3(rows 0..1)

    const float* W1 = w1 + s * 224; const float* B1 = b1 + s * 8;
    const float* W2 = w2 + s * 160; const float* B2 = b2 + s * 4;
    const float* W3 = w3 + s * 40;  const float* B3 = b3 + s * 2;
    const float* W4 = w4 + s * 10;

    float acc2[4][8];              // conv2 accumulators, live across halves
    #pragma unroll
    for (int co = 0; co < 4; ++co) {
        float bb = B2[co];
        #pragma unroll
        for (int p = 0; p < 8; ++p) acc2[co][p] = bb;
    }

    const int g0 = (p0 - 4) < 0 ? 0 : (p0 - 4);          // clamped window starts
    const int g3 = (p0 + 8) > (L - 4) ? (L - 4) : (p0 + 8);

    #pragma unroll
    for (int half = 0; half < 2; ++half) {
        // ---- conv1 half: co = half*4 .. half*4+3, k7, pad3, global windows ----
        float a1[4][8];
        #pragma unroll
        for (int co = 0; co < 4; ++co) {
            float bb = B1[half * 4 + co];
            #pragma unroll
            for (int p = 0; p < 8; ++p) a1[co][p] = bb;
        }
        #pragma unroll
        for (int ci = 0; ci < 4; ++ci) {
            const float* Dp = D + ((size_t)b * 4 + ci) * L;
            float w[16];                         // positions p0-4 .. p0+11
            *(float4*)&w[0]  = *(const float4*)(Dp + g0);
            *(float4*)&w[4]  = *(const float4*)(Dp + p0);
            *(float4*)&w[8]  = *(const float4*)(Dp + p0 + 4);
            *(float4*)&w[12] = *(const float4*)(Dp + g3);
            if (lane == 0)  { w[0] = w[8];  w[1] = w[7]; w[2] = w[6];  w[3] = w[5]; }
            if (lane == 63) { w[12] = w[10]; w[13] = w[9]; w[14] = w[8]; w[15] = w[7]; }
            #pragma unroll
            for (int co = 0; co < 4; ++co)
                #pragma unroll
                for (int k = 0; k < 7; ++k) {
                    float wt = W1[((half * 4 + co) * 4 + ci) * 7 + k];
                    #pragma unroll
                    for (int p = 0; p < 8; ++p)
                        a1[co][p] += wt * w[p + k + 1];
                }
        }
        if (half == 1) __syncthreads();          // conv2p0 reads of H done
        #pragma unroll
        for (int co = 0; co < 4; ++co) {
            float* row = &H[co][PAD + p0];
            float4 v0 = { a1[co][0], a1[co][1], a1[co][2], a1[co][3] };
            float4 v1 = { a1[co][4], a1[co][5], a1[co][6], a1[co][7] };
            *(float4*)row = v0;
            *(float4*)(row + 4) = v1;
            if (lane == 0)  { H[co][PAD - 1] = a1[co][1]; H[co][PAD - 2] = a1[co][2]; }
            if (lane == 63) { H[co][PAD + L] = a1[co][6]; H[co][PAD + L + 1] = a1[co][5]; }
        }
        __syncthreads();                         // h1 half visible

        // ---- conv2 partial: ci = half*4 .. half*4+3, k5, pad2, LDS windows ----
        #pragma unroll
        for (int ci = 0; ci < 4; ++ci) {
            const float* row = &H[ci][PAD + p0 - 2];   // 8B-aligned
            float x[12];                               // positions p0-2 .. p0+9
            *(float2*)&x[0]  = *(const float2*)row;
            *(float4*)&x[2]  = *(const float4*)(row + 2);
            *(float4*)&x[6]  = *(const float4*)(row + 6);
            *(float2*)&x[10] = *(const float2*)(row + 10);
            #pragma unroll
            for (int co = 0; co < 4; ++co)
                #pragma unroll
                for (int k = 0; k < 5; ++k) {
                    float wt = W2[(co * 8 + half * 4 + ci) * 5 + k];
                    #pragma unroll
                    for (int p = 0; p < 8; ++p)
                        acc2[co][p] += wt * x[p + k];
                }
        }
    }

    __syncthreads();                             // conv2p1 reads done
    // ---- SELU + store h2 (4 rows, halo W=2) ----
    #pragma unroll
    for (int co = 0; co < 4; ++co) {
        #pragma unroll
        for (int p = 0; p < 8; ++p) acc2[co][p] = selu(acc2[co][p]);
        float* row = &H[co][PAD + p0];
        float4 v0 = { acc2[co][0], acc2[co][1], acc2[co][2], acc2[co][3] };
        float4 v1 = { acc2[co][4], acc2[co][5], acc2[co][6], acc2[co][7] };
        *(float4*)row = v0;
        *(float4*)(row + 4) = v1;
        if (lane == 0)  { H[co][PAD - 1] = acc2[co][1]; H[co][PAD - 2] = acc2[co][2]; }
        if (lane == 63) { H[co][PAD + L] = acc2[co][6]; H[co][PAD + L + 1] = acc2[co][5]; }
    }
    __syncthreads();

    // ---- conv3: 4->2, k5, pad2 ----
    float a3[2][8];
    #pragma unroll
    for (int co = 0; co < 2; ++co) {
        float bb = B3[co];
        #pragma unroll
        for (int p = 0; p < 8; ++p) a3[co][p] = bb;
    }
    #pragma unroll
    for (int ci = 0; ci < 4; ++ci) {
        const float* row = &H[ci][PAD + p0 - 2];
        float x[12];
        *(float2*)&x[0]  = *(const float2*)row;
        *(float4*)&x[2]  = *(const float4*)(row + 2);
        *(float4*)&x[6]  = *(const float4*)(row + 6);
        *(float2*)&x[10] = *(const float2*)(row + 10);
        #pragma unroll
        for (int co = 0; co < 2; ++co)
            #pragma unroll
            for (int k = 0; k < 5; ++k) {
                float wt = W3[(co * 4 + ci) * 5 + k];
                #pragma unroll
                for (int p = 0; p < 8; ++p)
                    a3[co][p] += wt * x[p + k];
            }
    }
    __syncthreads();                             // conv3 reads done
    #pragma unroll
    for (int co = 0; co < 2; ++co) {             // store h3 (2 rows, halo W=4)
        float* row = &H[co][PAD + p0];
        float4 v0 = { a3[co][0], a3[co][1], a3[co][2], a3[co][3] };
        float4 v1 = { a3[co][4], a3[co][5], a3[co][6], a3[co][7] };
        *(float4*)row = v0;
        *(float4*)(row + 4) = v1;
        if (lane == 0) {
            H[co][PAD - 1] = a3[co][1]; H[co][PAD - 2] = a3[co][2];
            H[co][PAD - 3] = a3[co][3]; H[co][PAD - 4] = a3[co][4];
        }
        if (lane == 63) {
            H[co][PAD + L] = a3[co][6];     H[co][PAD + L + 1] = a3[co][5];
            H[co][PAD + L + 2] = a3[co][4]; H[co][PAD + L + 3] = a3[co][3];
        }
    }
    __syncthreads();

    // ---- conv4: 2->1, k5, d2, pad4, SELU -> out ----
    float a4[8];
    float bb4 = b4[s];
    #pragma unroll
    for (int p = 0; p < 8; ++p) a4[p] = bb4;
    #pragma unroll
    for (int ci = 0; ci < 2; ++ci) {
        const float* row = &H[ci][p0];           // index PAD+p0-4, 32B aligned
        float x[16];                             // positions p0-4 .. p0+11
        *(float4*)&x[0]  = *(const float4*)row;
        *(float4*)&x[4]  = *(const float4*)(row + 4);
        *(float4*)&x[8]  = *(const float4*)(row + 8);
        *(float4*)&x[12] = *(const float4*)(row + 12);
        #pragma unroll
        for (int k = 0; k < 5; ++k) {
            float wt = W4[ci * 5 + k];
            #pragma unroll
            for (int p = 0; p < 8; ++p)
                a4[p] += wt * x[p + 2 * k];
        }
    }
    float4 o0 = { selu(a4[0]), selu(a4[1]), selu(a4[2]), selu(a4[3]) };
    float4 o1 = { selu(a4[4]), selu(a4[5]), selu(a4[6]), selu(a4[7]) };
    float* op = &out[((size_t)b * NSIG + s) * L + p0];
    *(float4*)op = o0;
    *(float4*)(op + 4) = o1;
}

extern "C" void kernel_launch(void* const* d_in, const int* in_sizes, int n_in,
                              void* d_out, int out_size, void* d_ws, size_t ws_size,
                              hipStream_t stream) {
    const float* latent = (const float*)d_in[0];
    const float* sw1 = (const float*)d_in[1];
    const float* sb1 = (const float*)d_in[2];
    const float* sw2 = (const float*)d_in[3];
    const float* sb2 = (const float*)d_in[4];
    const float* ln_g = (const float*)d_in[5];
    const float* ln_b = (const float*)d_in[6];
    const float* g_w1 = (const float*)d_in[7];
    const float* g_b1 = (const float*)d_in[8];
    const float* g_w2 = (const float*)d_in[9];
    const float* g_b2 = (const float*)d_in[10];
    const float* g_w3 = (const float*)d_in[11];
    const float* g_b3 = (const float*)d_in[12];
    const float* g_w4 = (const float*)d_in[13];
    const float* g_b4 = (const float*)d_in[14];
    float* out = (float*)d_out;
    float* D = (float*)d_ws;   // (256,4,512) f32 = 2 MB

    shared_ln_kernel<<<BB, 256, 0, stream>>>(latent, sw1, sb1, sw2, sb2,
                                             ln_g, ln_b, D);
    signal_kernel<<<dim3(NSIG, BB), 64, 0, stream>>>(D, g_w1, g_b1, g_w2, g_b2,
                                                     g_w3, g_b3, g_w4, g_b4, out);
}

// Round 8
// 148.705 us; speedup vs baseline: 3.2567x; 1.0129x over previous
//
#include <hip/hip_runtime.h>
#include <math.h>

#define BB 256
#define L 512
#define NSIG 50
#define PAD 4
#define STR (L + 2 * PAD)   // 520 floats per padded row

__device__ __forceinline__ int refl(int i) {
    if (i < 0) i = -i;
    if (i >= L) i = 2 * L - 2 - i;
    return i;
}

__device__ __forceinline__ float selu(float x) {
    const float scale = 1.0507009873554804934193349852946f;
    const float alpha = 1.6732632423543772848170429916717f;
    return x > 0.f ? scale * x : scale * alpha * (__expf(x) - 1.f);
}

// ---------------- Kernel A: sharedCNN x2 + residual + LayerNorm ----------------
__global__ __launch_bounds__(256) void shared_ln_kernel(
    const float* __restrict__ latent,   // (B, 2048)
    const float* __restrict__ w1, const float* __restrict__ b1,   // (8,4,5),(8,)
    const float* __restrict__ w2, const float* __restrict__ b2,   // (4,8,5),(4,)
    const float* __restrict__ g,  const float* __restrict__ beta, // (512,),(512,)
    float* __restrict__ D)              // (B,4,512)
{
    __shared__ float xb[4][L];
    __shared__ float hb[8][L];
    __shared__ float yb[4][L];
    __shared__ float sw1[160], sb1[8], sw2[160], sb2[4];

    const int b = blockIdx.x;
    const int t = threadIdx.x;

    for (int i = t; i < 160; i += 256) { sw1[i] = w1[i]; sw2[i] = w2[i]; }
    if (t < 8) sb1[t] = b1[t];
    if (t < 4) sb2[t] = b2[t];

    const float* lp = latent + (size_t)b * 2048;
    for (int i = t; i < 2048; i += 256)
        xb[i & 3][i >> 2] = lp[i];   // x[c][l] = latent[l*4+c]
    __syncthreads();

    for (int pass = 0; pass < 2; ++pass) {
        const float (*src)[L] = (pass == 0) ? (const float (*)[L])xb
                                            : (const float (*)[L])yb;
        // conv1: 4->8, k5, d1, pad2, SELU
        for (int idx = t; idx < 8 * L; idx += 256) {
            int co = idx >> 9, l = idx & (L - 1);
            float acc = sb1[co];
            #pragma unroll
            for (int ci = 0; ci < 4; ++ci) {
                const float* w = &sw1[(co * 4 + ci) * 5];
                #pragma unroll
                for (int k = 0; k < 5; ++k)
                    acc += w[k] * src[ci][refl(l + k - 2)];
            }
            hb[co][l] = selu(acc);
        }
        __syncthreads();
        // conv2: 8->4, k5, d2, pad4 (+ residual on pass 1)
        for (int idx = t; idx < 4 * L; idx += 256) {
            int co = idx >> 9, l = idx & (L - 1);
            float acc = sb2[co];
            #pragma unroll
            for (int ci = 0; ci < 8; ++ci) {
                const float* w = &sw2[(co * 8 + ci) * 5];
                #pragma unroll
                for (int k = 0; k < 5; ++k)
                    acc += w[k] * hb[ci][refl(l + 2 * k - 4)];
            }
            if (pass == 1) acc += xb[co][l];
            yb[co][l] = acc;
        }
        __syncthreads();
    }

    // LayerNorm over length axis, one wave per channel (4 waves = 256 threads)
    const int wave = t >> 6;    // channel 0..3
    const int lane = t & 63;
    float v[8];
    float s = 0.f;
    #pragma unroll
    for (int j = 0; j < 8; ++j) { v[j] = yb[wave][lane * 8 + j]; s += v[j]; }
    #pragma unroll
    for (int off = 32; off > 0; off >>= 1) s += __shfl_down(s, off);
    s = __shfl(s, 0);
    const float mu = s * (1.f / 512.f);
    float s2 = 0.f;
    #pragma unroll
    for (int j = 0; j < 8; ++j) { float d = v[j] - mu; s2 += d * d; }
    #pragma unroll
    for (int off = 32; off > 0; off >>= 1) s2 += __shfl_down(s2, off);
    s2 = __shfl(s2, 0);
    const float rinv = rsqrtf(s2 * (1.f / 512.f) + 1e-10f);

    float* Dp = D + ((size_t)b * 4 + wave) * L;
    #pragma unroll
    for (int j = 0; j < 8; ++j) {
        int l = lane * 8 + j;
        Dp[l] = (v[j] - mu) * rinv * g[l] + beta[l];
    }
}

// ---------------- Kernel B: per-signal channel-reduction stack ----------------
// R2's proven geometry (256 thr, P=2, p0=2t, scalar LDS windows, 25 KB LDS)
// with ONE change: conv1 windows come straight from GLOBAL (D is L2-resident;
// VMEM pipe is separate from the saturated LDS pipe). Removes db staging +
// conv1's 32 LDS reads: ~145 -> ~105 LDS words/thread. h3 overlays dead h1
// rows; everything else identical to the 99.8 us R2 kernel.
__global__ __launch_bounds__(256) void signal_kernel(
    const float* __restrict__ D,   // (B,4,512)
    const float* __restrict__ w1, const float* __restrict__ b1, // (50,8,4,7),(50,8)
    const float* __restrict__ w2, const float* __restrict__ b2, // (50,4,8,5),(50,4)
    const float* __restrict__ w3, const float* __restrict__ b3, // (50,2,4,5),(50,2)
    const float* __restrict__ w4, const float* __restrict__ b4, // (50,1,2,5),(50,1)
    float* __restrict__ out)       // (B,50,512)
{
    const int s = blockIdx.x;
    const int b = blockIdx.y;
    const int t = threadIdx.x;     // 0..255
    const int p0 = t * 2;

    __shared__ float h1b[8][STR];  // h1; rows 0..1 reused for h3
    __shared__ float h2b[4][STR];  // h2

    const float* W1 = w1 + s * 224; const float* B1 = b1 + s * 8;
    const float* W2 = w2 + s * 160; const float* B2 = b2 + s * 4;
    const float* W3 = w3 + s * 40;  const float* B3 = b3 + s * 2;
    const float* W4 = w4 + s * 10;

    // ---- conv1: 4->8, k7, pad3, windows read DIRECTLY from global D ----
    // x[j] = position p0-4+j (j=0..9); 5 clamped float2 loads per ci,
    // reflect fixed up in-register (only threads 0 and 255 diverge).
    {
        const int q0 = p0 >= 4 ? p0 - 4 : 0;
        const int q1 = p0 >= 2 ? p0 - 2 : 0;
        const int q3 = (p0 + 2 <= L - 2) ? p0 + 2 : L - 2;
        const int q4 = (p0 + 4 <= L - 2) ? p0 + 4 : L - 2;

        float a1[8][2];
        #pragma unroll
        for (int co = 0; co < 8; ++co) {
            float bb = B1[co];
            a1[co][0] = bb; a1[co][1] = bb;
        }
        #pragma unroll
        for (int ci = 0; ci < 4; ++ci) {
            const float* Dp = D + ((size_t)b * 4 + ci) * L;
            float x[10];
            *(float2*)&x[0] = *(const float2*)(Dp + q0);
            *(float2*)&x[2] = *(const float2*)(Dp + q1);
            *(float2*)&x[4] = *(const float2*)(Dp + p0);
            *(float2*)&x[6] = *(const float2*)(Dp + q3);
            *(float2*)&x[8] = *(const float2*)(Dp + q4);
            if (t == 0)   { x[1] = x[7]; x[2] = x[6]; x[3] = x[5]; } // refl(-3,-2,-1)=3,2,1
            if (t == 255) { x[7] = x[3]; x[8] = x[2]; }              // refl(513,514)=509,508
            #pragma unroll
            for (int co = 0; co < 8; ++co)
                #pragma unroll
                for (int k = 0; k < 7; ++k) {
                    float w = W1[(co * 4 + ci) * 7 + k];
                    a1[co][0] += w * x[k + 1];
                    a1[co][1] += w * x[k + 2];
                }
        }
        #pragma unroll
        for (int co = 0; co < 8; ++co) {
            float2 v = { a1[co][0], a1[co][1] };
            *(float2*)&h1b[co][PAD + p0] = v;
            if (t == 0)   h1b[co][PAD - 1] = v.y;       // pos 1
            if (t == 1)   h1b[co][PAD - 2] = v.x;       // pos 2
            if (t == 255) h1b[co][PAD + L] = v.x;       // pos 510
            if (t == 254) h1b[co][PAD + L + 1] = v.y;   // pos 509
        }
    }
    __syncthreads();

    // ---- conv2: 8->4, k5, pad2, SELU. reads h1b, writes h2b ----
    {
        float acc2[4][2];
        #pragma unroll
        for (int co = 0; co < 4; ++co) {
            float bb = B2[co];
            acc2[co][0] = bb; acc2[co][1] = bb;
        }
        #pragma unroll
        for (int ci = 0; ci < 8; ++ci) {
            float x[6];
            #pragma unroll
            for (int j = 0; j < 6; ++j)
                x[j] = h1b[ci][p0 + j + (PAD - 2)];
            #pragma unroll
            for (int co = 0; co < 4; ++co)
                #pragma unroll
                for (int k = 0; k < 5; ++k) {
                    float w = W2[(co * 8 + ci) * 5 + k];
                    acc2[co][0] += w * x[k];
                    acc2[co][1] += w * x[k + 1];
                }
        }
        #pragma unroll
        for (int co = 0; co < 4; ++co) {
            float2 v = { selu(acc2[co][0]), selu(acc2[co][1]) };
            *(float2*)&h2b[co][PAD + p0] = v;
            if (t == 0)   h2b[co][PAD - 1] = v.y;
            if (t == 1)   h2b[co][PAD - 2] = v.x;
            if (t == 255) h2b[co][PAD + L] = v.x;
            if (t == 254) h2b[co][PAD + L + 1] = v.y;
        }
    }
    __syncthreads();

    // ---- conv3: 4->2, k5, pad2. reads h2b, writes h3 -> h1b rows 0..1 ----
    {
        float a3[2][2];
        #pragma unroll
        for (int co = 0; co < 2; ++co) {
            float bb = B3[co];
            a3[co][0] = bb; a3[co][1] = bb;
        }
        #pragma unroll
        for (int ci = 0; ci < 4; ++ci) {
            float x[6];
            #pragma unroll
            for (int j = 0; j < 6; ++j)
                x[j] = h2b[ci][p0 + j + (PAD - 2)];
            #pragma unroll
            for (int co = 0; co < 2; ++co)
                #pragma unroll
                for (int k = 0; k < 5; ++k) {
                    float w = W3[(co * 4 + ci) * 5 + k];
                    a3[co][0] += w * x[k];
                    a3[co][1] += w * x[k + 1];
                }
        }
        #pragma unroll
        for (int co = 0; co < 2; ++co) {
            float2 v = { a3[co][0], a3[co][1] };
            *(float2*)&h1b[co][PAD + p0] = v;
            if (t == 0)   { h1b[co][PAD - 1] = v.y; }                   // pos 1
            if (t == 1)   { h1b[co][PAD - 2] = v.x; h1b[co][PAD - 3] = v.y; } // pos 2,3
            if (t == 2)   { h1b[co][PAD - 4] = v.x; }                   // pos 4
            if (t == 255) { h1b[co][PAD + L] = v.x; }                   // pos 510
            if (t == 254) { h1b[co][PAD + L + 1] = v.y; h1b[co][PAD + L + 2] = v.x; } // 509,508
            if (t == 253) { h1b[co][PAD + L + 3] = v.y; }               // pos 507
        }
    }
    __syncthreads();

    // ---- conv4: 2->1, k5, d2, pad4, SELU. reads h1b rows 0..1 -> out ----
    {
        float a0 = b4[s], a1v = a0;
        #pragma unroll
        for (int ci = 0; ci < 2; ++ci) {
            float x[10];                       // positions p0-4 .. p0+5
            #pragma unroll
            for (int j = 0; j < 10; ++j)
                x[j] = h1b[ci][p0 + j];        // element PAD + p0 - 4 + j
            #pragma unroll
            for (int k = 0; k < 5; ++k) {
                float w = W4[ci * 5 + k];
                a0  += w * x[2 * k];
                a1v += w * x[2 * k + 1];
            }
        }
        float2 r = { selu(a0), selu(a1v) };
        *(float2*)&out[((size_t)b * NSIG + s) * L + p0] = r;
    }
}

extern "C" void kernel_launch(void* const* d_in, const int* in_sizes, int n_in,
                              void* d_out, int out_size, void* d_ws, size_t ws_size,
                              hipStream_t stream) {
    const float* latent = (const float*)d_in[0];
    const float* sw1 = (const float*)d_in[1];
    const float* sb1 = (const float*)d_in[2];
    const float* sw2 = (const float*)d_in[3];
    const float* sb2 = (const float*)d_in[4];
    const float* ln_g = (const float*)d_in[5];
    const float* ln_b = (const float*)d_in[6];
    const float* g_w1 = (const float*)d_in[7];
    const float* g_b1 = (const float*)d_in[8];
    const float* g_w2 = (const float*)d_in[9];
    const float* g_b2 = (const float*)d_in[10];
    const float* g_w3 = (const float*)d_in[11];
    const float* g_b3 = (const float*)d_in[12];
    const float* g_w4 = (const float*)d_in[13];
    const float* g_b4 = (const float*)d_in[14];
    float* out = (float*)d_out;
    float* D = (float*)d_ws;   // (256,4,512) f32 = 2 MB

    shared_ln_kernel<<<BB, 256, 0, stream>>>(latent, sw1, sb1, sw2, sb2,
                                             ln_g, ln_b, D);
    signal_kernel<<<dim3(NSIG, BB), 256, 0, stream>>>(D, g_w1, g_b1, g_w2, g_b2,
                                                      g_w3, g_b3, g_w4, g_b4, out);
}

// Round 9
// 113.819 us; speedup vs baseline: 4.2549x; 1.3065x over previous
//
#include <hip/hip_runtime.h>
#include <math.h>

#define BB 256
#define L 512
#define NSIG 50
#define PAD 4
#define STR (L + 2 * PAD)   // 520 floats per padded row

__device__ __forceinline__ int refl(int i) {
    if (i < 0) i = -i;
    if (i >= L) i = 2 * L - 2 - i;
    return i;
}

__device__ __forceinline__ float selu(float x) {
    const float scale = 1.0507009873554804934193349852946f;
    const float alpha = 1.6732632423543772848170429916717f;
    return x > 0.f ? scale * x : scale * alpha * (__expf(x) - 1.f);
}

// ---------------- Kernel A: sharedCNN x2 + residual + LayerNorm ----------------
__global__ __launch_bounds__(256) void shared_ln_kernel(
    const float* __restrict__ latent,   // (B, 2048)
    const float* __restrict__ w1, const float* __restrict__ b1,   // (8,4,5),(8,)
    const float* __restrict__ w2, const float* __restrict__ b2,   // (4,8,5),(4,)
    const float* __restrict__ g,  const float* __restrict__ beta, // (512,),(512,)
    float* __restrict__ D)              // (B,4,512)
{
    __shared__ float xb[4][L];
    __shared__ float hb[8][L];
    __shared__ float yb[4][L];
    __shared__ float sw1[160], sb1[8], sw2[160], sb2[4];

    const int b = blockIdx.x;
    const int t = threadIdx.x;

    for (int i = t; i < 160; i += 256) { sw1[i] = w1[i]; sw2[i] = w2[i]; }
    if (t < 8) sb1[t] = b1[t];
    if (t < 4) sb2[t] = b2[t];

    const float* lp = latent + (size_t)b * 2048;
    for (int i = t; i < 2048; i += 256)
        xb[i & 3][i >> 2] = lp[i];   // x[c][l] = latent[l*4+c]
    __syncthreads();

    for (int pass = 0; pass < 2; ++pass) {
        const float (*src)[L] = (pass == 0) ? (const float (*)[L])xb
                                            : (const float (*)[L])yb;
        // conv1: 4->8, k5, d1, pad2, SELU
        for (int idx = t; idx < 8 * L; idx += 256) {
            int co = idx >> 9, l = idx & (L - 1);
            float acc = sb1[co];
            #pragma unroll
            for (int ci = 0; ci < 4; ++ci) {
                const float* w = &sw1[(co * 4 + ci) * 5];
                #pragma unroll
                for (int k = 0; k < 5; ++k)
                    acc += w[k] * src[ci][refl(l + k - 2)];
            }
            hb[co][l] = selu(acc);
        }
        __syncthreads();
        // conv2: 8->4, k5, d2, pad4 (+ residual on pass 1)
        for (int idx = t; idx < 4 * L; idx += 256) {
            int co = idx >> 9, l = idx & (L - 1);
            float acc = sb2[co];
            #pragma unroll
            for (int ci = 0; ci < 8; ++ci) {
                const float* w = &sw2[(co * 8 + ci) * 5];
                #pragma unroll
                for (int k = 0; k < 5; ++k)
                    acc += w[k] * hb[ci][refl(l + 2 * k - 4)];
            }
            if (pass == 1) acc += xb[co][l];
            yb[co][l] = acc;
        }
        __syncthreads();
    }

    // LayerNorm over length axis, one wave per channel (4 waves = 256 threads)
    const int wave = t >> 6;    // channel 0..3
    const int lane = t & 63;
    float v[8];
    float s = 0.f;
    #pragma unroll
    for (int j = 0; j < 8; ++j) { v[j] = yb[wave][lane * 8 + j]; s += v[j]; }
    #pragma unroll
    for (int off = 32; off > 0; off >>= 1) s += __shfl_down(s, off);
    s = __shfl(s, 0);
    const float mu = s * (1.f / 512.f);
    float s2 = 0.f;
    #pragma unroll
    for (int j = 0; j < 8; ++j) { float d = v[j] - mu; s2 += d * d; }
    #pragma unroll
    for (int off = 32; off > 0; off >>= 1) s2 += __shfl_down(s2, off);
    s2 = __shfl(s2, 0);
    const float rinv = rsqrtf(s2 * (1.f / 512.f) + 1e-10f);

    float* Dp = D + ((size_t)b * 4 + wave) * L;
    #pragma unroll
    for (int j = 0; j < 8; ++j) {
        int l = lane * 8 + j;
        Dp[l] = (v[j] - mu) * rinv * g[l] + beta[l];
    }
}

// ---------------- Kernel B: per-signal channel-reduction stack ----------------
// R2's exact proven geometry (256 thr, P=2, p0=2t, staged db, 25 KB LDS,
// same 8-barrier structure). ONE change vs the 99.8us kernel: all LDS window
// reads are ds_read_b64 (float2) instead of scalar b32 — every window is
// 8B-aligned at even element index with PAD=4. 124 scalar reads -> 62 b64.
// 2-way bank alias of the b64 pattern is free (m136).
__global__ __launch_bounds__(256) void signal_kernel(
    const float* __restrict__ D,   // (B,4,512)
    const float* __restrict__ w1, const float* __restrict__ b1, // (50,8,4,7),(50,8)
    const float* __restrict__ w2, const float* __restrict__ b2, // (50,4,8,5),(50,4)
    const float* __restrict__ w3, const float* __restrict__ b3, // (50,2,4,5),(50,2)
    const float* __restrict__ w4, const float* __restrict__ b4, // (50,1,2,5),(50,1)
    float* __restrict__ out)       // (B,50,512)
{
    const int s = blockIdx.x;
    const int b = blockIdx.y;
    const int t = threadIdx.x;     // 0..255
    const int p0 = t * 2;

    __shared__ float bufA[4][STR]; // db, then h2
    __shared__ float bufB[8][STR]; // h1, then h3 (rows 0..1)

    const float* W1 = w1 + s * 224; const float* B1 = b1 + s * 8;
    const float* W2 = w2 + s * 160; const float* B2 = b2 + s * 4;
    const float* W3 = w3 + s * 40;  const float* B3 = b3 + s * 2;
    const float* W4 = w4 + s * 10;

    // ---- load D into bufA interior (float4 global + b128 LDS writes) ----
    {
        const float4* Dv = (const float4*)(D + (size_t)b * 2048);
        #pragma unroll
        for (int j = 0; j < 2; ++j) {
            int i = t + j * 256;               // float4 index 0..511
            float4 v = Dv[i];
            int c = i >> 7, col = (i & 127) << 2;
            *(float4*)&bufA[c][PAD + col] = v;
        }
    }
    __syncthreads();
    if (t < 32) {    // halo A (4 rows x 8)
        int r = t >> 3, j = t & 7;
        if (j < 4) bufA[r][PAD - 1 - j] = bufA[r][PAD + 1 + j];
        else { int i = j - 4; bufA[r][PAD + L + i] = bufA[r][PAD + L - 2 - i]; }
    }
    __syncthreads();

    // ---- conv1: 4->8, k7, pad3. reads bufA (5 b64/ci), writes bufB ----
    {
        float x[4][10];                        // positions p0-4 .. p0+5
        #pragma unroll
        for (int ci = 0; ci < 4; ++ci) {
            const float* row = &bufA[ci][p0];  // element idx p0 (= PAD+p0-4)
            #pragma unroll
            for (int j = 0; j < 5; ++j)
                *(float2*)&x[ci][2 * j] = *(const float2*)&row[2 * j];
        }
        #pragma unroll
        for (int co = 0; co < 8; ++co) {
            float a0 = B1[co], a1 = a0;
            #pragma unroll
            for (int ci = 0; ci < 4; ++ci)
                #pragma unroll
                for (int k = 0; k < 7; ++k) {
                    float w = W1[(co * 4 + ci) * 7 + k];
                    a0 += w * x[ci][k + 1];
                    a1 += w * x[ci][k + 2];
                }
            float2 v = { a0, a1 };
            *(float2*)&bufB[co][PAD + p0] = v;
        }
    }
    __syncthreads();
    if (t < 64) {    // halo B (8 rows x 8)
        int r = t >> 3, j = t & 7;
        if (j < 4) bufB[r][PAD - 1 - j] = bufB[r][PAD + 1 + j];
        else { int i = j - 4; bufB[r][PAD + L + i] = bufB[r][PAD + L - 2 - i]; }
    }
    __syncthreads();

    // ---- conv2: 8->4, k5, pad2, SELU. reads bufB (3 b64/ci), writes bufA ----
    {
        float acc2[4][2];
        #pragma unroll
        for (int co = 0; co < 4; ++co) {
            float bb = B2[co];
            acc2[co][0] = bb; acc2[co][1] = bb;
        }
        #pragma unroll
        for (int ci = 0; ci < 8; ++ci) {
            float x[6];                            // positions p0-2 .. p0+3
            const float* row = &bufB[ci][p0 + 2];  // element idx p0+2 (even)
            *(float2*)&x[0] = *(const float2*)&row[0];
            *(float2*)&x[2] = *(const float2*)&row[2];
            *(float2*)&x[4] = *(const float2*)&row[4];
            #pragma unroll
            for (int co = 0; co < 4; ++co)
                #pragma unroll
                for (int k = 0; k < 5; ++k) {
                    float w = W2[(co * 8 + ci) * 5 + k];
                    acc2[co][0] += w * x[k];
                    acc2[co][1] += w * x[k + 1];
                }
        }
        #pragma unroll
        for (int co = 0; co < 4; ++co) {
            float2 v = { selu(acc2[co][0]), selu(acc2[co][1]) };
            *(float2*)&bufA[co][PAD + p0] = v;
        }
    }
    __syncthreads();
    if (t < 32) {    // halo A (4 rows x 8)
        int r = t >> 3, j = t & 7;
        if (j < 4) bufA[r][PAD - 1 - j] = bufA[r][PAD + 1 + j];
        else { int i = j - 4; bufA[r][PAD + L + i] = bufA[r][PAD + L - 2 - i]; }
    }
    __syncthreads();

    // ---- conv3: 4->2, k5, pad2. reads bufA (3 b64/ci), writes bufB rows 0..1 ----
    {
        float a3[2][2];
        #pragma unroll
        for (int co = 0; co < 2; ++co) {
            float bb = B3[co];
            a3[co][0] = bb; a3[co][1] = bb;
        }
        #pragma unroll
        for (int ci = 0; ci < 4; ++ci) {
            float x[6];
            const float* row = &bufA[ci][p0 + 2];
            *(float2*)&x[0] = *(const float2*)&row[0];
            *(float2*)&x[2] = *(const float2*)&row[2];
            *(float2*)&x[4] = *(const float2*)&row[4];
            #pragma unroll
            for (int co = 0; co < 2; ++co)
                #pragma unroll
                for (int k = 0; k < 5; ++k) {
                    float w = W3[(co * 4 + ci) * 5 + k];
                    a3[co][0] += w * x[k];
                    a3[co][1] += w * x[k + 1];
                }
        }
        #pragma unroll
        for (int co = 0; co < 2; ++co) {
            float2 v = { a3[co][0], a3[co][1] };
            *(float2*)&bufB[co][PAD + p0] = v;
        }
    }
    __syncthreads();
    if (t < 16) {    // halo B rows 0..1
        int r = t >> 3, j = t & 7;
        if (j < 4) bufB[r][PAD - 1 - j] = bufB[r][PAD + 1 + j];
        else { int i = j - 4; bufB[r][PAD + L + i] = bufB[r][PAD + L - 2 - i]; }
    }
    __syncthreads();

    // ---- conv4: 2->1, k5, d2, pad4, SELU. reads bufB rows 0..1 (5 b64/ci) ----
    {
        float a0 = b4[s], a1v = a0;
        #pragma unroll
        for (int ci = 0; ci < 2; ++ci) {
            float x[10];                       // positions p0-4 .. p0+5
            const float* row = &bufB[ci][p0];  // element idx p0 (even)
            #pragma unroll
            for (int j = 0; j < 5; ++j)
                *(float2*)&x[2 * j] = *(const float2*)&row[2 * j];
            #pragma unroll
            for (int k = 0; k < 5; ++k) {
                float w = W4[ci * 5 + k];
                a0  += w * x[2 * k];
                a1v += w * x[2 * k + 1];
            }
        }
        float2 r = { selu(a0), selu(a1v) };
        *(float2*)&out[((size_t)b * NSIG + s) * L + p0] = r;
    }
}

extern "C" void kernel_launch(void* const* d_in, const int* in_sizes, int n_in,
                              void* d_out, int out_size, void* d_ws, size_t ws_size,
                              hipStream_t stream) {
    const float* latent = (const float*)d_in[0];
    const float* sw1 = (const float*)d_in[1];
    const float* sb1 = (const float*)d_in[2];
    const float* sw2 = (const float*)d_in[3];
    const float* sb2 = (const float*)d_in[4];
    const float* ln_g = (const float*)d_in[5];
    const float* ln_b = (const float*)d_in[6];
    const float* g_w1 = (const float*)d_in[7];
    const float* g_b1 = (const float*)d_in[8];
    const float* g_w2 = (const float*)d_in[9];
    const float* g_b2 = (const float*)d_in[10];
    const float* g_w3 = (const float*)d_in[11];
    const float* g_b3 = (const float*)d_in[12];
    const float* g_w4 = (const float*)d_in[13];
    const float* g_b4 = (const float*)d_in[14];
    float* out = (float*)d_out;
    float* D = (float*)d_ws;   // (256,4,512) f32 = 2 MB

    shared_ln_kernel<<<BB, 256, 0, stream>>>(latent, sw1, sb1, sw2, sb2,
                                             ln_g, ln_b, D);
    signal_kernel<<<dim3(NSIG, BB), 256, 0, stream>>>(D, g_w1, g_b1, g_w2, g_b2,
                                                      g_w3, g_b3, g_w4, g_b4, out);
}